// Round 13
// baseline (1074.600 us; speedup 1.0000x reference)
//
#include <hip/hip_runtime.h>
#include <stdint.h>

typedef unsigned int uint;
typedef float f2 __attribute__((ext_vector_type(2)));
typedef float f4u __attribute__((ext_vector_type(4), aligned(4)));   // 4B-aligned float4
#define DEV __device__ __forceinline__

// ---------------- helpers ----------------

DEV int dot4(uint a, uint b, int c) {
#if __has_builtin(__builtin_amdgcn_sdot4)
    return __builtin_amdgcn_sdot4((int)a, (int)b, c, false);
#else
    int r = c;
    r += (int)(int8_t)(a)       * (int)(int8_t)(b);
    r += (int)(int8_t)(a >> 8)  * (int)(int8_t)(b >> 8);
    r += (int)(int8_t)(a >> 16) * (int)(int8_t)(b >> 16);
    r += (int)(int8_t)(a >> 24) * (int)(int8_t)(b >> 24);
    return r;
#endif
}

DEV uint alignbyte(uint hi, uint lo, int m) {
#if __has_builtin(__builtin_amdgcn_alignbyte)
    return __builtin_amdgcn_alignbyte(hi, lo, m);
#else
    return (uint)((((uint64_t)hi << 32) | (uint64_t)lo) >> (8 * m));
#endif
}

DEV float bytef(uint v, int k) { return (float)((v >> (8 * k)) & 0xffu); }

// requantize int32 accumulator -> relu'd integer in [0,127]
DEV uint requant_relu(int acc, float M) {
    float q = rintf((float)acc * M);          // jnp.round = round-half-even = rintf
    q = fminf(fmaxf(q, -127.f), 127.f);
    q = fmaxf(q, 0.f);
    return (uint)q;
}

// ---------------- kernel 0: quantize input to u8 ----------------
__global__ __launch_bounds__(256) void k_quant(const float* __restrict__ x,
                                               uint8_t* __restrict__ xq,
                                               float in_s) {
    int i = blockIdx.x * 256 + threadIdx.x;
    float4 v = ((const float4*)x)[i];
    uint b0 = (uint)fminf(fmaxf(rintf(v.x / in_s), 0.f), 255.f);
    uint b1 = (uint)fminf(fmaxf(rintf(v.y / in_s), 0.f), 255.f);
    uint b2 = (uint)fminf(fmaxf(rintf(v.z / in_s), 0.f), 255.f);
    uint b3 = (uint)fminf(fmaxf(rintf(v.w / in_s), 0.f), 255.f);
    ((uint*)xq)[i] = b0 | (b1 << 8) | (b2 << 16) | (b3 << 24);
}

// ---------------- layer 0+1 fused: 5x5 (1->16) then 1x1 (16->12) ----------------
// grid (2, 512, 16), block 256. Output NHWC u8 c=12.
__global__ __launch_bounds__(256) void k_l0(const uint8_t* __restrict__ xq,
                                            const int* __restrict__ w,
                                            const int* __restrict__ b,
                                            uint8_t* __restrict__ out, float M,
                                            const int* __restrict__ w1,
                                            const int* __restrict__ b1, float M1) {
    __shared__ uint tin[5][68];     // rows y-2..y+2, byte cols [x0-4, x0+260)
    __shared__ uint wrow[5][16];    // packed taps 0..3 of row r, per oc
    __shared__ uint w4p[16];        // packed tap4 of rows 0..3, per oc
    __shared__ int  w44[16];        // tap (4,4)
    __shared__ int  beff[16];       // b + 128*sum(wq)
    __shared__ uint w1l[48];        // 1x1 weights [oc][d] packed
    __shared__ int  b1l[12];
    int t  = threadIdx.x;
    int x0 = blockIdx.x * 256;
    int y  = blockIdx.y;
    int n  = blockIdx.z;
    const uint8_t* xp = xq + (size_t)n * 512 * 512;

    for (int j = t; j < 330; j += 256) {
        int r = j / 66, d = j % 66;
        int yy = y - 2 + r;
        int gb = x0 - 4 + 4 * d;            // dword-aligned byte col; OOB is full-dword
        uint v = 0;
        if ((unsigned)yy < 512u && (unsigned)gb < 512u)
            v = *(const uint*)(xp + (size_t)yy * 512 + gb);
        tin[r][d] = v;
    }
    if (t < 80) {
        int oc = t / 5, r = t % 5;
        uint pk = 0;
#pragma unroll
        for (int k = 0; k < 4; ++k) {
            int wv = w[oc * 25 + r * 5 + k] - 128;
            pk |= ((uint)(uint8_t)(int8_t)wv) << (8 * k);
        }
        wrow[r][oc] = pk;
    }
    if (t < 16) {
        uint pk = 0;
#pragma unroll
        for (int r = 0; r < 4; ++r) {
            int wv = w[t * 25 + r * 5 + 4] - 128;
            pk |= ((uint)(uint8_t)(int8_t)wv) << (8 * r);
        }
        w4p[t] = pk;
        w44[t] = w[t * 25 + 24] - 128;
        int s = 0;
        for (int p = 0; p < 25; ++p) s += w[t * 25 + p] - 128;
        beff[t] = b[t] + 128 * s;
    }
    if (t < 48) {
        int oc = t >> 2, d = t & 3;
        uint pk = 0;
#pragma unroll
        for (int k = 0; k < 4; ++k) {
            int wv = w1[oc * 16 + d * 4 + k] - 128;
            pk |= ((uint)(uint8_t)(int8_t)wv) << (8 * k);
        }
        w1l[t] = pk;
    }
    if (t >= 64 && t < 76) b1l[t - 64] = b1[t - 64];
    __syncthreads();

    int m  = (t + 2) & 3;
    int d0 = (t + 2) >> 2;
    uint e0[5], t4[5];
#pragma unroll
    for (int r = 0; r < 5; ++r) {
        uint a0 = tin[r][d0], a1 = tin[r][d0 + 1];
        e0[r] = alignbyte(a1, a0, m) ^ 0x80808080u;
        t4[r] = (a1 >> (8 * m)) & 0xffu;
    }
    uint lo4 = (t4[0] | (t4[1] << 8) | (t4[2] << 16) | (t4[3] << 24)) ^ 0x80808080u;
    int  e44 = (int)(int8_t)(uint8_t)(t4[4] ^ 0x80u);

    int acc[16];
#pragma unroll
    for (int oc = 0; oc < 16; ++oc) acc[oc] = beff[oc];
#pragma unroll
    for (int r = 0; r < 5; ++r)
#pragma unroll
        for (int oc = 0; oc < 16; ++oc) acc[oc] = dot4(e0[r], wrow[r][oc], acc[oc]);
#pragma unroll
    for (int oc = 0; oc < 16; ++oc) {
        acc[oc] = dot4(lo4, w4p[oc], acc[oc]);
        acc[oc] += e44 * w44[oc];
    }

    uint dw[4];
#pragma unroll
    for (int g = 0; g < 4; ++g) {
        uint d = 0;
#pragma unroll
        for (int k = 0; k < 4; ++k) d |= requant_relu(acc[g * 4 + k], M) << (8 * k);
        dw[g] = d;
    }

    // fused 1x1: 16 -> 12, requant M1
    size_t pix = (size_t)(n * 512 + y) * 512 + (x0 + t);
    uint* op = (uint*)out;
#pragma unroll
    for (int g = 0; g < 3; ++g) {
        uint dword = 0;
#pragma unroll
        for (int k = 0; k < 4; ++k) {
            int oc = g * 4 + k;
            int a2 = b1l[oc];
#pragma unroll
            for (int d = 0; d < 4; ++d) a2 = dot4(dw[d], w1l[oc * 4 + d], a2);
            dword |= requant_relu(a2, M1) << (8 * k);
        }
        op[pix * 3 + g] = dword;
    }
}

// ---------------- 3x3 layers V4: 4 rows/block, vec loads + prefetch placement ----------------
// grid (128, 16), block 128. Thread t: px 4t..4t+3, output rows 4*yb..4*yb+3.
// ROW_LOAD v2: uniform y-branch; 12 interior dwords = 3 aligned uint4 loads (always
// in-bounds); 6 halo dwords guarded. 9 VMEM instrs vs 18 guarded scalars.
// Each wX reload is placed right after ACC_ROW(wX,0) (last use) for max prefetch distance.

#define ROW_LOAD(dst, yy) do {                                               \
    int yy_ = (yy);                                                          \
    if ((unsigned)yy_ < 512u) {    /* uniform per block */                   \
        size_t db_ = ((size_t)(n * 512 + yy_) * 512 + x0) * 3;               \
        const uint4* v4_ = (const uint4*)(ip + db_);                         \
        uint4 u0_ = v4_[0], u1_ = v4_[1], u2_ = v4_[2];                      \
        dst[1][0] = u0_.x; dst[1][1] = u0_.y; dst[1][2] = u0_.z;             \
        dst[2][0] = u0_.w; dst[2][1] = u1_.x; dst[2][2] = u1_.y;             \
        dst[3][0] = u1_.z; dst[3][1] = u1_.w; dst[3][2] = u2_.x;             \
        dst[4][0] = u2_.y; dst[4][1] = u2_.z; dst[4][2] = u2_.w;             \
        bool lok_ = (x0 > 0), rok_ = (x0 + 4 < 512);                         \
        _Pragma("unroll")                                                    \
        for (int d = 0; d < 3; ++d) {                                        \
            dst[0][d] = lok_ ? ip[db_ - 3 + d]  : 0u;                        \
            dst[5][d] = rok_ ? ip[db_ + 12 + d] : 0u;                        \
        }                                                                    \
    } else {                                                                 \
        _Pragma("unroll")                                                    \
        for (int ci = 0; ci < 6; ++ci)                                       \
            _Pragma("unroll")                                                \
            for (int d = 0; d < 3; ++d) dst[ci][d] = 0u;                     \
    } } while (0)

#define ACC_ROW(rowarr, ry) do {                                             \
    _Pragma("unroll")                                                        \
    for (int rx = 0; rx < 3; ++rx) {                                         \
        int pos_ = (ry) * 3 + rx;                                            \
        const uint4* wq_ = (const uint4*)&wl[pos_ * 36];                     \
        _Pragma("unroll")                                                    \
        for (int g = 0; g < 3; ++g) {                                        \
            uint4 wA_ = wq_[g * 3 + 0];                                      \
            uint4 wB_ = wq_[g * 3 + 1];                                      \
            uint4 wC_ = wq_[g * 3 + 2];                                      \
            uint wocd_[4][3] = {{wA_.x, wA_.y, wA_.z}, {wA_.w, wB_.x, wB_.y},\
                                {wB_.z, wB_.w, wC_.x}, {wC_.y, wC_.z, wC_.w}};\
            _Pragma("unroll")                                                \
            for (int k = 0; k < 4; ++k) {                                    \
                int oc_ = g * 4 + k;                                         \
                _Pragma("unroll")                                            \
                for (int p = 0; p < 4; ++p) {                                \
                    acc[p][oc_] = dot4(rowarr[rx + p][0], wocd_[k][0], acc[p][oc_]); \
                    acc[p][oc_] = dot4(rowarr[rx + p][1], wocd_[k][1], acc[p][oc_]); \
                    acc[p][oc_] = dot4(rowarr[rx + p][2], wocd_[k][2], acc[p][oc_]); \
                }                                                            \
            }                                                                \
        }                                                                    \
    } } while (0)

#define ACC_INIT() do {                                                      \
    _Pragma("unroll")                                                        \
    for (int p = 0; p < 4; ++p)                                              \
        _Pragma("unroll")                                                    \
        for (int oc = 0; oc < 12; ++oc) acc[p][oc] = bl[oc];                 \
    } while (0)

#define EPILOGUE(yout) do {                                                  \
    int y_ = (yout);                                                         \
    _Pragma("unroll")                                                        \
    for (int p = 0; p < 4; ++p) {                                            \
        uint dws_[3];                                                        \
        _Pragma("unroll")                                                    \
        for (int g = 0; g < 3; ++g) {                                        \
            uint dword_ = 0;                                                 \
            _Pragma("unroll")                                                \
            for (int k = 0; k < 4; ++k)                                      \
                dword_ |= requant_relu(acc[p][g * 4 + k], M) << (8 * k);     \
            dws_[g] = dword_;                                                \
        }                                                                    \
        size_t pix_ = (size_t)(n * 512 + y_) * 512 + (x0 + p);               \
        if (!FUSE) {                                                         \
            uint* op_ = (uint*)out;                                          \
            op_[pix_ * 3 + 0] = dws_[0];                                     \
            op_[pix_ * 3 + 1] = dws_[1];                                     \
            op_[pix_ * 3 + 2] = dws_[2];                                     \
        } else {                                                             \
            uint dw2_[4];                                                    \
            _Pragma("unroll")                                                \
            for (int g = 0; g < 4; ++g) {                                    \
                uint dword_ = 0;                                             \
                _Pragma("unroll")                                            \
                for (int k = 0; k < 4; ++k) {                                \
                    int oc_ = g * 4 + k;                                     \
                    int a2_ = b6l[oc_];                                      \
                    _Pragma("unroll")                                        \
                    for (int d = 0; d < 3; ++d)                              \
                        a2_ = dot4(dws_[d], w6l[oc_ * 3 + d], a2_);          \
                    dword_ |= requant_relu(a2_, M6) << (8 * k);              \
                }                                                            \
                dw2_[g] = dword_;                                            \
            }                                                                \
            ((uint4*)out)[pix_] = make_uint4(dw2_[0], dw2_[1], dw2_[2], dw2_[3]); \
        }                                                                    \
    } } while (0)

template <bool FUSE>
__global__ __launch_bounds__(128, 2) void k_3x3(const uint8_t* __restrict__ in,
                                                const int* __restrict__ w,
                                                const int* __restrict__ b,
                                                uint8_t* __restrict__ out, float M,
                                                const int* __restrict__ w6,
                                                const int* __restrict__ b6, float M6) {
    __shared__ uint wl[324];    // [pos][oc][d] packed i8 (ic 4 per dword)
    __shared__ int  bl[12];
    __shared__ uint w6l[48];    // [oc16][d3]
    __shared__ int  b6l[16];
    int t = threadIdx.x;
    for (int j = t; j < 324; j += 128) {
        int pos = j / 36;
        int oc  = (j % 36) / 3;
        int d   = j % 3;
        uint pk = 0;
#pragma unroll
        for (int k = 0; k < 4; ++k) {
            int ic = d * 4 + k;
            int wv = w[oc * 108 + ic * 9 + pos] - 128;
            pk |= ((uint)(uint8_t)(int8_t)wv) << (8 * k);
        }
        wl[j] = pk;
    }
    if (t < 12) bl[t] = b[t];
    if (FUSE) {
        if (t >= 16 && t < 64) {
            int j = t - 16, oc = j / 3, d = j % 3;
            uint pk = 0;
#pragma unroll
            for (int k = 0; k < 4; ++k) {
                int wv = w6[oc * 12 + d * 4 + k] - 128;
                pk |= ((uint)(uint8_t)(int8_t)wv) << (8 * k);
            }
            w6l[j] = pk;
        }
        if (t >= 64 && t < 80) b6l[t - 64] = b6[t - 64];
    }
    __syncthreads();

    int y0 = blockIdx.x * 4, n = blockIdx.y;
    int x0 = t * 4;
    const uint* ip = (const uint*)in;

    uint wa[6][3], wb[6][3], wc[6][3];
    int acc[4][12];

    ROW_LOAD(wa, y0 - 1);
    ROW_LOAD(wb, y0);
    ROW_LOAD(wc, y0 + 1);
    ACC_INIT(); ACC_ROW(wa, 0); ROW_LOAD(wa, y0 + 2); ACC_ROW(wb, 1); ACC_ROW(wc, 2); EPILOGUE(y0);
    ACC_INIT(); ACC_ROW(wb, 0); ROW_LOAD(wb, y0 + 3); ACC_ROW(wc, 1); ACC_ROW(wa, 2); EPILOGUE(y0 + 1);
    ACC_INIT(); ACC_ROW(wc, 0); ROW_LOAD(wc, y0 + 4); ACC_ROW(wa, 1); ACC_ROW(wb, 2); EPILOGUE(y0 + 2);
    ACC_INIT(); ACC_ROW(wa, 0); ACC_ROW(wb, 1); ACC_ROW(wc, 2); EPILOGUE(y0 + 3);
}

// ---------------- deconv weight prep (weights pre-scaled by out_s) ----------------
// main table  wp[pos=r*3+s][c][o=py*4+px]  (2304) : tap (jy=4r-py, jx=4s-px), 0 if OOB
// s0 table    wp[2304 + r*64 + c*4 + py]   (192)  : tap (jy=4r-py, jx=0)
__global__ __launch_bounds__(256) void k_wprep(const float* __restrict__ wt,
                                               float* __restrict__ wp, float out_s) {
    int idx = blockIdx.x * 256 + threadIdx.x;   // 2496 entries
    if (idx < 2304) {
        int o = idx & 15, c = (idx >> 4) & 15, pos = idx >> 8;
        int r = pos / 3, s = pos % 3;
        int py = o >> 2, px = o & 3;
        int jy = 4 * r - py, jx = 4 * s - px;
        float v = 0.f;
        if (jy >= 0 && jy < 9 && jx >= 0 && jx < 9)
            v = wt[c * 81 + (8 - jy) * 9 + (8 - jx)] * out_s;
        wp[idx] = v;
    } else if (idx < 2496) {
        int i2 = idx - 2304;
        int r = i2 >> 6, c = (i2 >> 2) & 15, py = i2 & 3;
        int jy = 4 * r - py;
        float v = 0.f;
        if (jy >= 0 && jy < 9)
            v = wt[c * 81 + (8 - jy) * 9 + 8] * out_s;
        wp[idx] = v;
    }
}

// ---------------- deconv V8: 2-tile/256-thread + dwordx4 stores ----------------
template <bool ALLPY>
DEV void dc_row8(const float* __restrict__ wrow,     // wl + (r*3)*256
                 const float* __restrict__ w0tab,    // wl0 + r*64
                 const uint4* ld,                    // 4 input pixels (window cols)
                 f2 (&accA)[2][4], f2 (&accB)[2][4]) {
    uint bv[4][4];
#pragma unroll
    for (int s = 0; s < 4; ++s) { bv[s][0] = ld[s].x; bv[s][1] = ld[s].y; bv[s][2] = ld[s].z; bv[s][3] = ld[s].w; }
#pragma unroll
    for (int c = 0; c < 16; ++c) {
        float xc[4];
#pragma unroll
        for (int s = 0; s < 4; ++s) xc[s] = bytef(bv[s][c >> 2], c & 3);
        // ---- s = 0 (jx=0 taps only; zero-padded elsewhere) ----
        if (ALLPY) {
            float4 wv = *(const float4*)(w0tab + c * 4);   // 4 py at once
            accA[0][0].x = fmaf(wv.x, xc[0], accA[0][0].x);
            accA[0][1].x = fmaf(wv.y, xc[0], accA[0][1].x);
            accA[0][2].x = fmaf(wv.z, xc[0], accA[0][2].x);
            accA[0][3].x = fmaf(wv.w, xc[0], accA[0][3].x);
            accA[1][0].x = fmaf(wv.x, xc[1], accA[1][0].x);
            accA[1][1].x = fmaf(wv.y, xc[1], accA[1][1].x);
            accA[1][2].x = fmaf(wv.z, xc[1], accA[1][2].x);
            accA[1][3].x = fmaf(wv.w, xc[1], accA[1][3].x);
        } else {
            float w0 = w0tab[c * 4];
            accA[0][0].x = fmaf(w0, xc[0], accA[0][0].x);
            accA[1][0].x = fmaf(w0, xc[1], accA[1][0].x);
        }
        // ---- s = 1,2: full 4-px weight rows; each read feeds both tiles ----
#pragma unroll
        for (int s = 1; s < 3; ++s) {
            const float* wb = wrow + s * 256 + c * 16;
            f2 xxA = {xc[s], xc[s]};
            f2 xxB = {xc[s + 1], xc[s + 1]};
#pragma unroll
            for (int py = 0; py < (ALLPY ? 4 : 1); ++py) {
                float4 wv = *(const float4*)(wb + py * 4);
                f2 wlo = {wv.x, wv.y};
                f2 whi = {wv.z, wv.w};
                accA[0][py] = __builtin_elementwise_fma(wlo, xxA, accA[0][py]);
                accB[0][py] = __builtin_elementwise_fma(whi, xxA, accB[0][py]);
                accA[1][py] = __builtin_elementwise_fma(wlo, xxB, accA[1][py]);
                accB[1][py] = __builtin_elementwise_fma(whi, xxB, accB[1][py]);
            }
        }
    }
}

__global__ __launch_bounds__(256, 2) void k_deconv8(const uint8_t* __restrict__ in,
                                                    const float* __restrict__ wp,
                                                    float* __restrict__ out) {
    __shared__ float wl[2304];
    __shared__ float wl0[192];
    int t = threadIdx.x;
#pragma unroll
    for (int j = 0; j < 9; ++j) wl[j * 256 + t] = wp[j * 256 + t];
    if (t < 192) wl0[t] = wp[2304 + t];
    __syncthreads();

    int gx = t;                         // 0..255, two tiles: 2gx, 2gx+1
    int ty = blockIdx.y;                // 0..511
    int n  = blockIdx.z;
    const uint4* ip = (const uint4*)in + (size_t)n * 512 * 512;

    f2 accA[2][4], accB[2][4];          // [tile][py]: (px0,px1) / (px2,px3)
#pragma unroll
    for (int k = 0; k < 2; ++k)
#pragma unroll
        for (int i = 0; i < 4; ++i) { accA[k][i] = (f2){0.f, 0.f}; accB[k][i] = (f2){0.f, 0.f}; }

    // r = 0 (iy = ty-1): only py=0 taps
    {
        int iy = ty - 1;
        uint4 ld[4];
#pragma unroll
        for (int s = 0; s < 4; ++s) {
            int ix = 2 * gx - 1 + s;
            bool ok = (iy >= 0) && ((unsigned)ix < 512u);
            ld[s] = ok ? ip[(size_t)iy * 512 + ix] : make_uint4(0u, 0u, 0u, 0u);
        }
        dc_row8<false>(&wl[0], &wl0[0], ld, accA, accB);
    }
    // r = 1,2: all py — keep loop ROLLED to bound code size / register pressure
#pragma unroll 1
    for (int r = 1; r < 3; ++r) {
        int iy = ty - 1 + r;
        uint4 ld[4];
#pragma unroll
        for (int s = 0; s < 4; ++s) {
            int ix = 2 * gx - 1 + s;
            bool ok = (iy < 512) && ((unsigned)ix < 512u);
            ld[s] = ok ? ip[(size_t)iy * 512 + ix] : make_uint4(0u, 0u, 0u, 0u);
        }
        dc_row8<true>(&wl[r * 768], &wl0[r * 64], ld, accA, accB);
    }

    int oy0 = 4 * ty, ox0 = 8 * gx;
    float* op = out + (size_t)n * 2045 * 2045;
#pragma unroll
    for (int py = 0; py < 4; ++py) {
        int oy = oy0 + py;
        if (oy >= 2045) break;
        size_t rb = (size_t)oy * 2045 + ox0;
        if (ox0 + 8 <= 2045) {
            f4u vA = {accA[0][py].x, accA[0][py].y, accB[0][py].x, accB[0][py].y};
            f4u vB = {accA[1][py].x, accA[1][py].y, accB[1][py].x, accB[1][py].y};
            *(f4u*)(op + rb)     = vA;
            *(f4u*)(op + rb + 4) = vB;
        } else {
            float va[8] = {accA[0][py].x, accA[0][py].y, accB[0][py].x, accB[0][py].y,
                           accA[1][py].x, accA[1][py].y, accB[1][py].x, accB[1][py].y};
            int xlim = 2045 - ox0;
#pragma unroll
            for (int px = 0; px < 8; ++px) {
                if (px >= xlim) break;
                op[rb + px] = va[px];
            }
        }
    }
}

// ---------------- host launch ----------------
extern "C" void kernel_launch(void* const* d_in, const int* in_sizes, int n_in,
                              void* d_out, int out_size, void* d_ws, size_t ws_size,
                              hipStream_t stream) {
    const float* x  = (const float*)d_in[0];
    const int*   w0 = (const int*)d_in[1];
    const int*   b0 = (const int*)d_in[2];
    const int*   w1 = (const int*)d_in[3];
    const int*   b1 = (const int*)d_in[4];
    const int*   w2 = (const int*)d_in[5];
    const int*   b2 = (const int*)d_in[6];
    const int*   w3 = (const int*)d_in[7];
    const int*   b3 = (const int*)d_in[8];
    const int*   w4 = (const int*)d_in[9];
    const int*   b4 = (const int*)d_in[10];
    const int*   w5 = (const int*)d_in[11];
    const int*   b5 = (const int*)d_in[12];
    const int*   w6 = (const int*)d_in[13];
    const int*   b6 = (const int*)d_in[14];
    const float* wt = (const float*)d_in[15];
    float* out = (float*)d_out;

    uint8_t* A  = (uint8_t*)d_ws;                       // 64 MiB (12ch or final 16ch)
    uint8_t* B  = (uint8_t*)d_ws + (size_t)(64 << 20);  // 64 MiB (xq then 12ch layers)
    uint8_t* xq = B;                                    // xq dead after k_l0
    float*  wpD = (float*)(B + (size_t)(60 << 20));     // ~10 KiB (B writes stay < 51 MB)

    const float M0  = (float)((1.0 / 255.0) * 0.02 / 0.05);
    const float M1  = (float)(0.05 * 0.02 / 0.04);
    const float M25 = (float)(0.04 * 0.02 / 0.04);
    const float M6  = (float)(0.04 * 0.02 / 0.05);
    const float IN_S_F = (float)(1.0 / 255.0);

    k_wprep<<<10, 256, 0, stream>>>(wt, wpD, 0.05f);
    k_quant<<<4096, 256, 0, stream>>>(x, xq, IN_S_F);
    k_l0<<<dim3(2, 512, 16), 256, 0, stream>>>(xq, w0, b0, A, M0, w1, b1, M1);     // A = 12ch
    k_3x3<false><<<dim3(128, 16), 128, 0, stream>>>(A, w2, b2, B, M25, nullptr, nullptr, 0.f);
    k_3x3<false><<<dim3(128, 16), 128, 0, stream>>>(B, w3, b3, A, M25, nullptr, nullptr, 0.f);
    k_3x3<false><<<dim3(128, 16), 128, 0, stream>>>(A, w4, b4, B, M25, nullptr, nullptr, 0.f);
    k_3x3<true><<<dim3(128, 16), 128, 0, stream>>>(B, w5, b5, A, M25, w6, b6, M6); // A = 16ch
    k_deconv8<<<dim3(1, 512, 16), 256, 0, stream>>>(A, wpD, out);
}

// Round 14
// 493.598 us; speedup vs baseline: 2.1771x; 2.1771x over previous
//
#include <hip/hip_runtime.h>
#include <stdint.h>

typedef unsigned int uint;
typedef float f2 __attribute__((ext_vector_type(2)));
typedef float f4u __attribute__((ext_vector_type(4), aligned(4)));   // 4B-aligned float4
#define DEV __device__ __forceinline__

// ---------------- helpers ----------------

DEV int dot4(uint a, uint b, int c) {
#if __has_builtin(__builtin_amdgcn_sdot4)
    return __builtin_amdgcn_sdot4((int)a, (int)b, c, false);
#else
    int r = c;
    r += (int)(int8_t)(a)       * (int)(int8_t)(b);
    r += (int)(int8_t)(a >> 8)  * (int)(int8_t)(b >> 8);
    r += (int)(int8_t)(a >> 16) * (int)(int8_t)(b >> 16);
    r += (int)(int8_t)(a >> 24) * (int)(int8_t)(b >> 24);
    return r;
#endif
}

DEV uint alignbyte(uint hi, uint lo, int m) {
#if __has_builtin(__builtin_amdgcn_alignbyte)
    return __builtin_amdgcn_alignbyte(hi, lo, m);
#else
    return (uint)((((uint64_t)hi << 32) | (uint64_t)lo) >> (8 * m));
#endif
}

DEV float bytef(uint v, int k) { return (float)((v >> (8 * k)) & 0xffu); }

// requantize int32 accumulator -> relu'd integer in [0,127]
DEV uint requant_relu(int acc, float M) {
    float q = rintf((float)acc * M);          // jnp.round = round-half-even = rintf
    q = fminf(fmaxf(q, -127.f), 127.f);
    q = fmaxf(q, 0.f);
    return (uint)q;
}

// ---------------- kernel 0: quantize input to u8 ----------------
__global__ __launch_bounds__(256) void k_quant(const float* __restrict__ x,
                                               uint8_t* __restrict__ xq,
                                               float in_s) {
    int i = blockIdx.x * 256 + threadIdx.x;
    float4 v = ((const float4*)x)[i];
    uint b0 = (uint)fminf(fmaxf(rintf(v.x / in_s), 0.f), 255.f);
    uint b1 = (uint)fminf(fmaxf(rintf(v.y / in_s), 0.f), 255.f);
    uint b2 = (uint)fminf(fmaxf(rintf(v.z / in_s), 0.f), 255.f);
    uint b3 = (uint)fminf(fmaxf(rintf(v.w / in_s), 0.f), 255.f);
    ((uint*)xq)[i] = b0 | (b1 << 8) | (b2 << 16) | (b3 << 24);
}

// ---------------- layer 0+1 fused: 5x5 (1->16) then 1x1 (16->12) ----------------
// grid (2, 512, 16), block 256. Output NHWC u8 c=12.
__global__ __launch_bounds__(256) void k_l0(const uint8_t* __restrict__ xq,
                                            const int* __restrict__ w,
                                            const int* __restrict__ b,
                                            uint8_t* __restrict__ out, float M,
                                            const int* __restrict__ w1,
                                            const int* __restrict__ b1, float M1) {
    __shared__ uint tin[5][68];     // rows y-2..y+2, byte cols [x0-4, x0+260)
    __shared__ uint wrow[5][16];    // packed taps 0..3 of row r, per oc
    __shared__ uint w4p[16];        // packed tap4 of rows 0..3, per oc
    __shared__ int  w44[16];        // tap (4,4)
    __shared__ int  beff[16];       // b + 128*sum(wq)
    __shared__ uint w1l[48];        // 1x1 weights [oc][d] packed
    __shared__ int  b1l[12];
    int t  = threadIdx.x;
    int x0 = blockIdx.x * 256;
    int y  = blockIdx.y;
    int n  = blockIdx.z;
    const uint8_t* xp = xq + (size_t)n * 512 * 512;

    for (int j = t; j < 330; j += 256) {
        int r = j / 66, d = j % 66;
        int yy = y - 2 + r;
        int gb = x0 - 4 + 4 * d;            // dword-aligned byte col; OOB is full-dword
        uint v = 0;
        if ((unsigned)yy < 512u && (unsigned)gb < 512u)
            v = *(const uint*)(xp + (size_t)yy * 512 + gb);
        tin[r][d] = v;
    }
    if (t < 80) {
        int oc = t / 5, r = t % 5;
        uint pk = 0;
#pragma unroll
        for (int k = 0; k < 4; ++k) {
            int wv = w[oc * 25 + r * 5 + k] - 128;
            pk |= ((uint)(uint8_t)(int8_t)wv) << (8 * k);
        }
        wrow[r][oc] = pk;
    }
    if (t < 16) {
        uint pk = 0;
#pragma unroll
        for (int r = 0; r < 4; ++r) {
            int wv = w[t * 25 + r * 5 + 4] - 128;
            pk |= ((uint)(uint8_t)(int8_t)wv) << (8 * r);
        }
        w4p[t] = pk;
        w44[t] = w[t * 25 + 24] - 128;
        int s = 0;
        for (int p = 0; p < 25; ++p) s += w[t * 25 + p] - 128;
        beff[t] = b[t] + 128 * s;
    }
    if (t < 48) {
        int oc = t >> 2, d = t & 3;
        uint pk = 0;
#pragma unroll
        for (int k = 0; k < 4; ++k) {
            int wv = w1[oc * 16 + d * 4 + k] - 128;
            pk |= ((uint)(uint8_t)(int8_t)wv) << (8 * k);
        }
        w1l[t] = pk;
    }
    if (t >= 64 && t < 76) b1l[t - 64] = b1[t - 64];
    __syncthreads();

    int m  = (t + 2) & 3;
    int d0 = (t + 2) >> 2;
    uint e0[5], t4[5];
#pragma unroll
    for (int r = 0; r < 5; ++r) {
        uint a0 = tin[r][d0], a1 = tin[r][d0 + 1];
        e0[r] = alignbyte(a1, a0, m) ^ 0x80808080u;
        t4[r] = (a1 >> (8 * m)) & 0xffu;
    }
    uint lo4 = (t4[0] | (t4[1] << 8) | (t4[2] << 16) | (t4[3] << 24)) ^ 0x80808080u;
    int  e44 = (int)(int8_t)(uint8_t)(t4[4] ^ 0x80u);

    int acc[16];
#pragma unroll
    for (int oc = 0; oc < 16; ++oc) acc[oc] = beff[oc];
#pragma unroll
    for (int r = 0; r < 5; ++r)
#pragma unroll
        for (int oc = 0; oc < 16; ++oc) acc[oc] = dot4(e0[r], wrow[r][oc], acc[oc]);
#pragma unroll
    for (int oc = 0; oc < 16; ++oc) {
        acc[oc] = dot4(lo4, w4p[oc], acc[oc]);
        acc[oc] += e44 * w44[oc];
    }

    uint dw[4];
#pragma unroll
    for (int g = 0; g < 4; ++g) {
        uint d = 0;
#pragma unroll
        for (int k = 0; k < 4; ++k) d |= requant_relu(acc[g * 4 + k], M) << (8 * k);
        dw[g] = d;
    }

    // fused 1x1: 16 -> 12, requant M1
    size_t pix = (size_t)(n * 512 + y) * 512 + (x0 + t);
    uint* op = (uint*)out;
#pragma unroll
    for (int g = 0; g < 3; ++g) {
        uint dword = 0;
#pragma unroll
        for (int k = 0; k < 4; ++k) {
            int oc = g * 4 + k;
            int a2 = b1l[oc];
#pragma unroll
            for (int d = 0; d < 4; ++d) a2 = dot4(dw[d], w1l[oc * 4 + d], a2);
            dword |= requant_relu(a2, M1) << (8 * k);
        }
        op[pix * 3 + g] = dword;
    }
}

// ---------------- 3x3 layers V3: 4 rows/block, macro-inlined register streaming ----------------
// grid (128, 16), block 128. Thread t: px 4t..4t+3, output rows 4*yb..4*yb+3.
// All window arrays referenced BY NAME (no pointer arrays, no helper passing) so SROA
// keeps them in registers (round-11 lesson). Loads grouped after EPILOGUE (round-13
// lesson: vectorized/mid-block load restructure -> spill; this exact form is known-good).

#define ROW_LOAD(dst, yy) do {                                               \
    int yy_ = (yy);                                                          \
    bool yok_ = (unsigned)yy_ < 512u;                                        \
    _Pragma("unroll")                                                        \
    for (int ci = 0; ci < 6; ++ci) {                                         \
        int xx_ = x0 - 1 + ci;                                               \
        bool ok_ = yok_ && (unsigned)xx_ < 512u;                             \
        size_t base_ = ((size_t)(n * 512 + yy_) * 512 + xx_) * 3;            \
        _Pragma("unroll")                                                    \
        for (int d = 0; d < 3; ++d) dst[ci][d] = ok_ ? ip[base_ + d] : 0u;   \
    } } while (0)

#define ACC_ROW(rowarr, ry) do {                                             \
    _Pragma("unroll")                                                        \
    for (int rx = 0; rx < 3; ++rx) {                                         \
        int pos_ = (ry) * 3 + rx;                                            \
        const uint4* wq_ = (const uint4*)&wl[pos_ * 36];                     \
        _Pragma("unroll")                                                    \
        for (int g = 0; g < 3; ++g) {                                        \
            uint4 wA_ = wq_[g * 3 + 0];                                      \
            uint4 wB_ = wq_[g * 3 + 1];                                      \
            uint4 wC_ = wq_[g * 3 + 2];                                      \
            uint wocd_[4][3] = {{wA_.x, wA_.y, wA_.z}, {wA_.w, wB_.x, wB_.y},\
                                {wB_.z, wB_.w, wC_.x}, {wC_.y, wC_.z, wC_.w}};\
            _Pragma("unroll")                                                \
            for (int k = 0; k < 4; ++k) {                                    \
                int oc_ = g * 4 + k;                                         \
                _Pragma("unroll")                                            \
                for (int p = 0; p < 4; ++p) {                                \
                    acc[p][oc_] = dot4(rowarr[rx + p][0], wocd_[k][0], acc[p][oc_]); \
                    acc[p][oc_] = dot4(rowarr[rx + p][1], wocd_[k][1], acc[p][oc_]); \
                    acc[p][oc_] = dot4(rowarr[rx + p][2], wocd_[k][2], acc[p][oc_]); \
                }                                                            \
            }                                                                \
        }                                                                    \
    } } while (0)

#define ACC_INIT() do {                                                      \
    _Pragma("unroll")                                                        \
    for (int p = 0; p < 4; ++p)                                              \
        _Pragma("unroll")                                                    \
        for (int oc = 0; oc < 12; ++oc) acc[p][oc] = bl[oc];                 \
    } while (0)

#define EPILOGUE(yout) do {                                                  \
    int y_ = (yout);                                                         \
    _Pragma("unroll")                                                        \
    for (int p = 0; p < 4; ++p) {                                            \
        uint dws_[3];                                                        \
        _Pragma("unroll")                                                    \
        for (int g = 0; g < 3; ++g) {                                        \
            uint dword_ = 0;                                                 \
            _Pragma("unroll")                                                \
            for (int k = 0; k < 4; ++k)                                      \
                dword_ |= requant_relu(acc[p][g * 4 + k], M) << (8 * k);     \
            dws_[g] = dword_;                                                \
        }                                                                    \
        size_t pix_ = (size_t)(n * 512 + y_) * 512 + (x0 + p);               \
        if (!FUSE) {                                                         \
            uint* op_ = (uint*)out;                                          \
            op_[pix_ * 3 + 0] = dws_[0];                                     \
            op_[pix_ * 3 + 1] = dws_[1];                                     \
            op_[pix_ * 3 + 2] = dws_[2];                                     \
        } else {                                                             \
            uint dw2_[4];                                                    \
            _Pragma("unroll")                                                \
            for (int g = 0; g < 4; ++g) {                                    \
                uint dword_ = 0;                                             \
                _Pragma("unroll")                                            \
                for (int k = 0; k < 4; ++k) {                                \
                    int oc_ = g * 4 + k;                                     \
                    int a2_ = b6l[oc_];                                      \
                    _Pragma("unroll")                                        \
                    for (int d = 0; d < 3; ++d)                              \
                        a2_ = dot4(dws_[d], w6l[oc_ * 3 + d], a2_);          \
                    dword_ |= requant_relu(a2_, M6) << (8 * k);              \
                }                                                            \
                dw2_[g] = dword_;                                            \
            }                                                                \
            ((uint4*)out)[pix_] = make_uint4(dw2_[0], dw2_[1], dw2_[2], dw2_[3]); \
        }                                                                    \
    } } while (0)

template <bool FUSE>
__global__ __launch_bounds__(128, 2) void k_3x3(const uint8_t* __restrict__ in,
                                                const int* __restrict__ w,
                                                const int* __restrict__ b,
                                                uint8_t* __restrict__ out, float M,
                                                const int* __restrict__ w6,
                                                const int* __restrict__ b6, float M6) {
    __shared__ uint wl[324];    // [pos][oc][d] packed i8 (ic 4 per dword)
    __shared__ int  bl[12];
    __shared__ uint w6l[48];    // [oc16][d3]
    __shared__ int  b6l[16];
    int t = threadIdx.x;
    for (int j = t; j < 324; j += 128) {
        int pos = j / 36;
        int oc  = (j % 36) / 3;
        int d   = j % 3;
        uint pk = 0;
#pragma unroll
        for (int k = 0; k < 4; ++k) {
            int ic = d * 4 + k;
            int wv = w[oc * 108 + ic * 9 + pos] - 128;
            pk |= ((uint)(uint8_t)(int8_t)wv) << (8 * k);
        }
        wl[j] = pk;
    }
    if (t < 12) bl[t] = b[t];
    if (FUSE) {
        if (t >= 16 && t < 64) {
            int j = t - 16, oc = j / 3, d = j % 3;
            uint pk = 0;
#pragma unroll
            for (int k = 0; k < 4; ++k) {
                int wv = w6[oc * 12 + d * 4 + k] - 128;
                pk |= ((uint)(uint8_t)(int8_t)wv) << (8 * k);
            }
            w6l[j] = pk;
        }
        if (t >= 64 && t < 80) b6l[t - 64] = b6[t - 64];
    }
    __syncthreads();

    int y0 = blockIdx.x * 4, n = blockIdx.y;
    int x0 = t * 4;
    const uint* ip = (const uint*)in;

    uint wa[6][3], wb[6][3], wc[6][3];
    int acc[4][12];

    ROW_LOAD(wa, y0 - 1);
    ROW_LOAD(wb, y0);
    ROW_LOAD(wc, y0 + 1);
    ACC_INIT(); ACC_ROW(wa, 0); ACC_ROW(wb, 1); ACC_ROW(wc, 2); EPILOGUE(y0);
    ROW_LOAD(wa, y0 + 2);
    ACC_INIT(); ACC_ROW(wb, 0); ACC_ROW(wc, 1); ACC_ROW(wa, 2); EPILOGUE(y0 + 1);
    ROW_LOAD(wb, y0 + 3);
    ACC_INIT(); ACC_ROW(wc, 0); ACC_ROW(wa, 1); ACC_ROW(wb, 2); EPILOGUE(y0 + 2);
    ROW_LOAD(wc, y0 + 4);
    ACC_INIT(); ACC_ROW(wa, 0); ACC_ROW(wb, 1); ACC_ROW(wc, 2); EPILOGUE(y0 + 3);
}

// ---------------- deconv weight prep (weights pre-scaled by out_s) ----------------
// main table  wp[pos=r*3+s][c][o=py*4+px]  (2304) : tap (jy=4r-py, jx=4s-px), 0 if OOB
// s0 table    wp[2304 + r*64 + c*4 + py]   (192)  : tap (jy=4r-py, jx=0)
__global__ __launch_bounds__(256) void k_wprep(const float* __restrict__ wt,
                                               float* __restrict__ wp, float out_s) {
    int idx = blockIdx.x * 256 + threadIdx.x;   // 2496 entries
    if (idx < 2304) {
        int o = idx & 15, c = (idx >> 4) & 15, pos = idx >> 8;
        int r = pos / 3, s = pos % 3;
        int py = o >> 2, px = o & 3;
        int jy = 4 * r - py, jx = 4 * s - px;
        float v = 0.f;
        if (jy >= 0 && jy < 9 && jx >= 0 && jx < 9)
            v = wt[c * 81 + (8 - jy) * 9 + (8 - jx)] * out_s;
        wp[idx] = v;
    } else if (idx < 2496) {
        int i2 = idx - 2304;
        int r = i2 >> 6, c = (i2 >> 2) & 15, py = i2 & 3;
        int jy = 4 * r - py;
        float v = 0.f;
        if (jy >= 0 && jy < 9)
            v = wt[c * 81 + (8 - jy) * 9 + 8] * out_s;
        wp[idx] = v;
    }
}

// ---------------- deconv V8: 2-tile/256-thread + dwordx4 stores ----------------
template <bool ALLPY>
DEV void dc_row8(const float* __restrict__ wrow,     // wl + (r*3)*256
                 const float* __restrict__ w0tab,    // wl0 + r*64
                 const uint4* ld,                    // 4 input pixels (window cols)
                 f2 (&accA)[2][4], f2 (&accB)[2][4]) {
    uint bv[4][4];
#pragma unroll
    for (int s = 0; s < 4; ++s) { bv[s][0] = ld[s].x; bv[s][1] = ld[s].y; bv[s][2] = ld[s].z; bv[s][3] = ld[s].w; }
#pragma unroll
    for (int c = 0; c < 16; ++c) {
        float xc[4];
#pragma unroll
        for (int s = 0; s < 4; ++s) xc[s] = bytef(bv[s][c >> 2], c & 3);
        // ---- s = 0 (jx=0 taps only; zero-padded elsewhere) ----
        if (ALLPY) {
            float4 wv = *(const float4*)(w0tab + c * 4);   // 4 py at once
            accA[0][0].x = fmaf(wv.x, xc[0], accA[0][0].x);
            accA[0][1].x = fmaf(wv.y, xc[0], accA[0][1].x);
            accA[0][2].x = fmaf(wv.z, xc[0], accA[0][2].x);
            accA[0][3].x = fmaf(wv.w, xc[0], accA[0][3].x);
            accA[1][0].x = fmaf(wv.x, xc[1], accA[1][0].x);
            accA[1][1].x = fmaf(wv.y, xc[1], accA[1][1].x);
            accA[1][2].x = fmaf(wv.z, xc[1], accA[1][2].x);
            accA[1][3].x = fmaf(wv.w, xc[1], accA[1][3].x);
        } else {
            float w0 = w0tab[c * 4];
            accA[0][0].x = fmaf(w0, xc[0], accA[0][0].x);
            accA[1][0].x = fmaf(w0, xc[1], accA[1][0].x);
        }
        // ---- s = 1,2: full 4-px weight rows; each read feeds both tiles ----
#pragma unroll
        for (int s = 1; s < 3; ++s) {
            const float* wb = wrow + s * 256 + c * 16;
            f2 xxA = {xc[s], xc[s]};
            f2 xxB = {xc[s + 1], xc[s + 1]};
#pragma unroll
            for (int py = 0; py < (ALLPY ? 4 : 1); ++py) {
                float4 wv = *(const float4*)(wb + py * 4);
                f2 wlo = {wv.x, wv.y};
                f2 whi = {wv.z, wv.w};
                accA[0][py] = __builtin_elementwise_fma(wlo, xxA, accA[0][py]);
                accB[0][py] = __builtin_elementwise_fma(whi, xxA, accB[0][py]);
                accA[1][py] = __builtin_elementwise_fma(wlo, xxB, accA[1][py]);
                accB[1][py] = __builtin_elementwise_fma(whi, xxB, accB[1][py]);
            }
        }
    }
}

__global__ __launch_bounds__(256, 2) void k_deconv8(const uint8_t* __restrict__ in,
                                                    const float* __restrict__ wp,
                                                    float* __restrict__ out) {
    __shared__ float wl[2304];
    __shared__ float wl0[192];
    int t = threadIdx.x;
#pragma unroll
    for (int j = 0; j < 9; ++j) wl[j * 256 + t] = wp[j * 256 + t];
    if (t < 192) wl0[t] = wp[2304 + t];
    __syncthreads();

    int gx = t;                         // 0..255, two tiles: 2gx, 2gx+1
    int ty = blockIdx.y;                // 0..511
    int n  = blockIdx.z;
    const uint4* ip = (const uint4*)in + (size_t)n * 512 * 512;

    f2 accA[2][4], accB[2][4];          // [tile][py]: (px0,px1) / (px2,px3)
#pragma unroll
    for (int k = 0; k < 2; ++k)
#pragma unroll
        for (int i = 0; i < 4; ++i) { accA[k][i] = (f2){0.f, 0.f}; accB[k][i] = (f2){0.f, 0.f}; }

    // r = 0 (iy = ty-1): only py=0 taps
    {
        int iy = ty - 1;
        uint4 ld[4];
#pragma unroll
        for (int s = 0; s < 4; ++s) {
            int ix = 2 * gx - 1 + s;
            bool ok = (iy >= 0) && ((unsigned)ix < 512u);
            ld[s] = ok ? ip[(size_t)iy * 512 + ix] : make_uint4(0u, 0u, 0u, 0u);
        }
        dc_row8<false>(&wl[0], &wl0[0], ld, accA, accB);
    }
    // r = 1,2: all py — keep loop ROLLED to bound code size / register pressure
#pragma unroll 1
    for (int r = 1; r < 3; ++r) {
        int iy = ty - 1 + r;
        uint4 ld[4];
#pragma unroll
        for (int s = 0; s < 4; ++s) {
            int ix = 2 * gx - 1 + s;
            bool ok = (iy < 512) && ((unsigned)ix < 512u);
            ld[s] = ok ? ip[(size_t)iy * 512 + ix] : make_uint4(0u, 0u, 0u, 0u);
        }
        dc_row8<true>(&wl[r * 768], &wl0[r * 64], ld, accA, accB);
    }

    int oy0 = 4 * ty, ox0 = 8 * gx;
    float* op = out + (size_t)n * 2045 * 2045;
#pragma unroll
    for (int py = 0; py < 4; ++py) {
        int oy = oy0 + py;
        if (oy >= 2045) break;
        size_t rb = (size_t)oy * 2045 + ox0;
        if (ox0 + 8 <= 2045) {
            f4u vA = {accA[0][py].x, accA[0][py].y, accB[0][py].x, accB[0][py].y};
            f4u vB = {accA[1][py].x, accA[1][py].y, accB[1][py].x, accB[1][py].y};
            *(f4u*)(op + rb)     = vA;
            *(f4u*)(op + rb + 4) = vB;
        } else {
            float va[8] = {accA[0][py].x, accA[0][py].y, accB[0][py].x, accB[0][py].y,
                           accA[1][py].x, accA[1][py].y, accB[1][py].x, accB[1][py].y};
            int xlim = 2045 - ox0;
#pragma unroll
            for (int px = 0; px < 8; ++px) {
                if (px >= xlim) break;
                op[rb + px] = va[px];
            }
        }
    }
}

// ---------------- host launch ----------------
extern "C" void kernel_launch(void* const* d_in, const int* in_sizes, int n_in,
                              void* d_out, int out_size, void* d_ws, size_t ws_size,
                              hipStream_t stream) {
    const float* x  = (const float*)d_in[0];
    const int*   w0 = (const int*)d_in[1];
    const int*   b0 = (const int*)d_in[2];
    const int*   w1 = (const int*)d_in[3];
    const int*   b1 = (const int*)d_in[4];
    const int*   w2 = (const int*)d_in[5];
    const int*   b2 = (const int*)d_in[6];
    const int*   w3 = (const int*)d_in[7];
    const int*   b3 = (const int*)d_in[8];
    const int*   w4 = (const int*)d_in[9];
    const int*   b4 = (const int*)d_in[10];
    const int*   w5 = (const int*)d_in[11];
    const int*   b5 = (const int*)d_in[12];
    const int*   w6 = (const int*)d_in[13];
    const int*   b6 = (const int*)d_in[14];
    const float* wt = (const float*)d_in[15];
    float* out = (float*)d_out;

    uint8_t* A  = (uint8_t*)d_ws;                       // 64 MiB (12ch or final 16ch)
    uint8_t* B  = (uint8_t*)d_ws + (size_t)(64 << 20);  // 64 MiB (xq then 12ch layers)
    uint8_t* xq = B;                                    // xq dead after k_l0
    float*  wpD = (float*)(B + (size_t)(60 << 20));     // ~10 KiB (B writes stay < 51 MB)

    const float M0  = (float)((1.0 / 255.0) * 0.02 / 0.05);
    const float M1  = (float)(0.05 * 0.02 / 0.04);
    const float M25 = (float)(0.04 * 0.02 / 0.04);
    const float M6  = (float)(0.04 * 0.02 / 0.05);
    const float IN_S_F = (float)(1.0 / 255.0);

    k_wprep<<<10, 256, 0, stream>>>(wt, wpD, 0.05f);
    k_quant<<<4096, 256, 0, stream>>>(x, xq, IN_S_F);
    k_l0<<<dim3(2, 512, 16), 256, 0, stream>>>(xq, w0, b0, A, M0, w1, b1, M1);     // A = 12ch
    k_3x3<false><<<dim3(128, 16), 128, 0, stream>>>(A, w2, b2, B, M25, nullptr, nullptr, 0.f);
    k_3x3<false><<<dim3(128, 16), 128, 0, stream>>>(B, w3, b3, A, M25, nullptr, nullptr, 0.f);
    k_3x3<false><<<dim3(128, 16), 128, 0, stream>>>(A, w4, b4, B, M25, nullptr, nullptr, 0.f);
    k_3x3<true><<<dim3(128, 16), 128, 0, stream>>>(B, w5, b5, A, M25, w6, b6, M6); // A = 16ch
    k_deconv8<<<dim3(1, 512, 16), 256, 0, stream>>>(A, wpD, out);
}